// Round 3
// baseline (590.236 us; speedup 1.0000x reference)
//
#include <hip/hip_runtime.h>

// SelfAttnPool: B=32, T=4096, F=512, U=512 (fp32 in/out)
//   scores[b,t] = tanh(x[b,t,:]@W + b) @ V   (u never materialized)
//   a = softmax_T(scores); out[b,f] = sum_t a[b,t]*x[b,t,f]
//
// R3: depth-1 software-pipelined barrier-free K-loop. B-frags (L2-hot,
// pre-permuted) and A-rows prefetched one K-step ahead in registers; MFMA
// order puts bl-dependent terms last. 3-term bf16 split (hh+lh+hl) on
// mfma 32x32x16 for fp32-grade score precision.

#define XT 4096
#define XF 512
#define XU 512

typedef __attribute__((ext_vector_type(8))) short short8;
typedef __attribute__((ext_vector_type(16))) float f32x16;
typedef __attribute__((ext_vector_type(4))) unsigned int u32x4;

__device__ inline unsigned fbits(float x) { return __builtin_bit_cast(unsigned, x); }
__device__ inline float bitsf(unsigned u) { return __builtin_bit_cast(float, u); }

__device__ inline void cvt_hilo(float x, unsigned short &h, unsigned short &l) {
  unsigned u = fbits(x);
  h = (unsigned short)(u >> 16);
  float lo = x - bitsf(u & 0xFFFF0000u);
  l = (unsigned short)(fbits(lo) >> 16);
}

// pack hi16(b)<<16 | hi16(a)
__device__ inline unsigned hipack(unsigned a, unsigned b) {
  return __builtin_amdgcn_perm(b, a, 0x07060302u);
}

// row fragment: 8 k-contiguous floats -> bf16 hi + bf16 lo (exact residual)
__device__ inline void cvt_row(float4 c0, float4 c1, short8 &h8, short8 &l8) {
  float f[8] = {c0.x, c0.y, c0.z, c0.w, c1.x, c1.y, c1.z, c1.w};
  unsigned hp[4], lp[4];
#pragma unroll
  for (int p = 0; p < 4; ++p) {
    unsigned u0 = fbits(f[2 * p]), u1 = fbits(f[2 * p + 1]);
    hp[p] = hipack(u0, u1);
    float l0 = f[2 * p] - bitsf(u0 & 0xFFFF0000u);
    float l1 = f[2 * p + 1] - bitsf(u1 & 0xFFFF0000u);
    lp[p] = hipack(fbits(l0), fbits(l1));
  }
  u32x4 hv = {hp[0], hp[1], hp[2], hp[3]};
  u32x4 lv = {lp[0], lp[1], lp[2], lp[3]};
  h8 = __builtin_bit_cast(short8, hv);
  l8 = __builtin_bit_cast(short8, lv);
}

__device__ inline float tanh_fast(float z) {
  float e = __expf(2.0f * z);
  return 1.0f - 2.0f * __builtin_amdgcn_rcpf(e + 1.0f);
}

// ---- W pre-conversion: fp32 [512 k][512 n] -> bf16 hi/lo, fragment-ready:
// whi/wlo: [slice s(32)][chunk16B: t(16)*64 + g(2)*32 + l(32)][j(8)]
// element = W[k = s*16 + g*8 + j][n = t*32 + l]
__global__ void wconv_kernel(const float *__restrict__ W,
                             unsigned short *__restrict__ whi,
                             unsigned short *__restrict__ wlo) {
  int t2 = blockIdx.x * 256 + threadIdx.x;  // 32768 threads
  int l = t2 & 31;
  int g = (t2 >> 5) & 1;
  int t = (t2 >> 6) & 15;
  int s = t2 >> 10;
  short8 hv, lv;
#pragma unroll
  for (int j = 0; j < 8; ++j) {
    unsigned short h, lo;
    cvt_hilo(W[(size_t)(s * 16 + g * 8 + j) * XU + t * 32 + l], h, lo);
    hv[j] = (short)h;
    lv[j] = (short)lo;
  }
  size_t off = (size_t)s * 8192 + t * 512 + g * 256 + l * 8;
  *(short8 *)(whi + off) = hv;
  *(short8 *)(wlo + off) = lv;
}

#define MFMA(a, b, c) __builtin_amdgcn_mfma_f32_32x32x16_bf16(a, b, c, 0, 0, 0)

// ---- fused GEMM + tanh + (.@V) -> scores
// block: 512 thr = 8 waves; tile 128 rows x 512 cols; wave = 64r x 128c.
__global__ __launch_bounds__(512, 2)
void gemm_scores_kernel(const float *__restrict__ x,
                        const unsigned short *__restrict__ whi,
                        const unsigned short *__restrict__ wlo,
                        const float *__restrict__ bias,
                        const float *__restrict__ V,
                        float *__restrict__ scores) {
  __shared__ float scb[512];

  const int tid = threadIdx.x;
  const int lane = tid & 63;
  const int wave = tid >> 6;
  const int wr = wave >> 2;   // row half (64 rows)
  const int wc = wave & 3;    // col quarter (128 cols)
  const int l31 = lane & 31;
  const int half = lane >> 5;
  const size_t rowbase = (size_t)blockIdx.x * 128;

  f32x16 acc[2][4];
#pragma unroll
  for (int a = 0; a < 2; ++a)
#pragma unroll
    for (int c = 0; c < 4; ++c)
#pragma unroll
      for (int r = 0; r < 16; ++r) acc[a][c][r] = 0.f;

  const float *xr0 = x + (rowbase + wr * 64 + l31) * XF + half * 8;
  const float *xr1 = xr0 + 32 * XF;
  const unsigned short *whp = whi + (size_t)(wc * 4) * 512 + lane * 8;
  const unsigned short *wlp = wlo + (size_t)(wc * 4) * 512 + lane * 8;

  short8 bh[2][4], bl[4];
  float4 raw[2][4];
  short8 ah0, al0, ah1, al1;

  // prologue: s = 0
#pragma unroll
  for (int cf = 0; cf < 4; ++cf) bh[0][cf] = *(const short8 *)(whp + cf * 512);
  raw[0][0] = *(const float4 *)(xr0);
  raw[0][1] = *(const float4 *)(xr0 + 4);
  raw[0][2] = *(const float4 *)(xr1);
  raw[0][3] = *(const float4 *)(xr1 + 4);
  cvt_row(raw[0][0], raw[0][1], ah0, al0);
  cvt_row(raw[0][2], raw[0][3], ah1, al1);

#pragma unroll 2
  for (int s = 0; s < 32; ++s) {
    const int cur = s & 1, nxt = cur ^ 1;
    const int sn = (s + 1) & 31;  // wrap: last prefetch is a harmless reload
    // bl for THIS step (used by the last 8 MFMAs -> ~16 MFMAs of cover)
#pragma unroll
    for (int cf = 0; cf < 4; ++cf)
      bl[cf] = *(const short8 *)(wlp + (size_t)s * 8192 + cf * 512);
    // prefetch next bh + next A rows
#pragma unroll
    for (int cf = 0; cf < 4; ++cf)
      bh[nxt][cf] = *(const short8 *)(whp + (size_t)sn * 8192 + cf * 512);
    raw[nxt][0] = *(const float4 *)(xr0 + sn * 16);
    raw[nxt][1] = *(const float4 *)(xr0 + sn * 16 + 4);
    raw[nxt][2] = *(const float4 *)(xr1 + sn * 16);
    raw[nxt][3] = *(const float4 *)(xr1 + sn * 16 + 4);

#pragma unroll
    for (int cf = 0; cf < 4; ++cf) {
      acc[0][cf] = MFMA(ah0, bh[cur][cf], acc[0][cf]);
      acc[1][cf] = MFMA(ah1, bh[cur][cf], acc[1][cf]);
    }
#pragma unroll
    for (int cf = 0; cf < 4; ++cf) {
      acc[0][cf] = MFMA(al0, bh[cur][cf], acc[0][cf]);
      acc[1][cf] = MFMA(al1, bh[cur][cf], acc[1][cf]);
    }
#pragma unroll
    for (int cf = 0; cf < 4; ++cf) {
      acc[0][cf] = MFMA(ah0, bl[cf], acc[0][cf]);
      acc[1][cf] = MFMA(ah1, bl[cf], acc[1][cf]);
    }
    // convert next A (loads have had the whole MFMA block to land)
    cvt_row(raw[nxt][0], raw[nxt][1], ah0, al0);
    cvt_row(raw[nxt][2], raw[nxt][3], ah1, al1);
  }

  // epilogue: sc[row] = sum_n tanh(acc + b[n]) * V[n]
  // C/D 32x32: col n = l31 (+32*cf+128*wc); row = (r&3)+8*(r>>2)+4*half (+32*rf+64*wr)
  float sc[2][16];
#pragma unroll
  for (int rf = 0; rf < 2; ++rf)
#pragma unroll
    for (int r = 0; r < 16; ++r) sc[rf][r] = 0.f;

#pragma unroll
  for (int cf = 0; cf < 4; ++cf) {
    int n = wc * 128 + cf * 32 + l31;
    float vv = V[n];
    float bb = bias[n];
#pragma unroll
    for (int rf = 0; rf < 2; ++rf)
#pragma unroll
      for (int r = 0; r < 16; ++r)
        sc[rf][r] += tanh_fast(acc[rf][cf][r] + bb) * vv;
  }
#pragma unroll
  for (int m = 1; m <= 16; m <<= 1) {
#pragma unroll
    for (int rf = 0; rf < 2; ++rf)
#pragma unroll
      for (int r = 0; r < 16; ++r)
        sc[rf][r] += __shfl_xor(sc[rf][r], m, 64);
  }
  if (l31 == 0) {
#pragma unroll
    for (int rf = 0; rf < 2; ++rf)
#pragma unroll
      for (int r = 0; r < 16; ++r) {
        int row = wr * 64 + rf * 32 + (r & 3) + 8 * (r >> 2) + 4 * half;
        scb[wc * 128 + row] = sc[rf][r];
      }
  }
  __syncthreads();
  if (tid < 128)
    scores[rowbase + tid] =
        scb[tid] + scb[128 + tid] + scb[256 + tid] + scb[384 + tid];
}

// ---- per-batch softmax stats (max, sumexp) over T=4096
__global__ void stats_kernel(const float *__restrict__ scores,
                             float *__restrict__ stats) {
  int b = blockIdx.x, tid = threadIdx.x;
  const float *s = scores + (size_t)b * XT;
  float v[16];
#pragma unroll
  for (int i = 0; i < 16; ++i) v[i] = s[tid + i * 256];
  float mx = v[0];
#pragma unroll
  for (int i = 1; i < 16; ++i) mx = fmaxf(mx, v[i]);
  for (int m = 1; m < 64; m <<= 1) mx = fmaxf(mx, __shfl_xor(mx, m, 64));
  __shared__ float redm[4], reds[4];
  if ((tid & 63) == 0) redm[tid >> 6] = mx;
  __syncthreads();
  mx = fmaxf(fmaxf(redm[0], redm[1]), fmaxf(redm[2], redm[3]));
  float sum = 0.f;
#pragma unroll
  for (int i = 0; i < 16; ++i) sum += __expf(v[i] - mx);
  for (int m = 1; m < 64; m <<= 1) sum += __shfl_xor(sum, m, 64);
  if ((tid & 63) == 0) reds[tid >> 6] = sum;
  __syncthreads();
  if (tid == 0) {
    stats[b * 2] = mx;
    stats[b * 2 + 1] = reds[0] + reds[1] + reds[2] + reds[3];
  }
}

// ---- weighted pooling: out[b,f] += sum_t w[t]*x[b,t,f]
// 2048 blocks (32 b x 64 chunks of 64 rows); float4 coalesced; 8 blocks/CU.
__global__ __launch_bounds__(256)
void pool_kernel(const float *__restrict__ x, const float *__restrict__ scores,
                 const float *__restrict__ stats, float *__restrict__ out) {
  int b = blockIdx.x >> 6;
  int ch = blockIdx.x & 63;
  int tid = threadIdx.x;
  __shared__ float w[64];
  __shared__ float red[512];
  float mx = stats[b * 2];
  float inv = 1.0f / stats[b * 2 + 1];
  if (tid < 64)
    w[tid] = __expf(scores[(size_t)b * XT + ch * 64 + tid] - mx) * inv;
  __syncthreads();
  int c = tid & 127;   // float4 column
  int ro = tid >> 7;   // row parity
  const float *xp = x + ((size_t)b * XT + ch * 64) * XF;
  float4 a = {0.f, 0.f, 0.f, 0.f};
#pragma unroll 8
  for (int i = 0; i < 32; ++i) {
    int r = i * 2 + ro;
    float4 v = *(const float4 *)(xp + (size_t)r * XF + c * 4);
    float wv = w[r];
    a.x += wv * v.x;
    a.y += wv * v.y;
    a.z += wv * v.z;
    a.w += wv * v.w;
  }
  if (ro == 1) {
    red[c * 4 + 0] = a.x;
    red[c * 4 + 1] = a.y;
    red[c * 4 + 2] = a.z;
    red[c * 4 + 3] = a.w;
  }
  __syncthreads();
  if (ro == 0) {
    atomicAdd(&out[b * XF + c * 4 + 0], a.x + red[c * 4 + 0]);
    atomicAdd(&out[b * XF + c * 4 + 1], a.y + red[c * 4 + 1]);
    atomicAdd(&out[b * XF + c * 4 + 2], a.z + red[c * 4 + 2]);
    atomicAdd(&out[b * XF + c * 4 + 3], a.w + red[c * 4 + 3]);
  }
}

extern "C" void kernel_launch(void *const *d_in, const int *in_sizes, int n_in,
                              void *d_out, int out_size, void *d_ws,
                              size_t ws_size, hipStream_t stream) {
  const float *x = (const float *)d_in[0];
  const float *W = (const float *)d_in[1];
  const float *bias = (const float *)d_in[2];
  const float *V = (const float *)d_in[3];
  float *out = (float *)d_out;

  // workspace: whi 512KB | wlo 512KB | scores 512KB | stats 256B
  unsigned short *whi = (unsigned short *)d_ws;
  unsigned short *wlo = whi + 262144;
  float *scores = (float *)((char *)d_ws + 1048576);
  float *stats = (float *)((char *)d_ws + 1572864);

  hipMemsetAsync(d_out, 0, (size_t)out_size * sizeof(float), stream);
  wconv_kernel<<<128, 256, 0, stream>>>(W, whi, wlo);
  gemm_scores_kernel<<<1024, 512, 0, stream>>>(x, whi, wlo, bias, V, scores);
  stats_kernel<<<32, 256, 0, stream>>>(scores, stats);
  pool_kernel<<<2048, 256, 0, stream>>>(x, scores, stats, out);
}

// Round 4
// 568.474 us; speedup vs baseline: 1.0383x; 1.0383x over previous
//
#include <hip/hip_runtime.h>

// SelfAttnPool: B=32, T=4096, F=512, U=512 (fp32 in/out)
//   scores[b,t] = tanh(x[b,t,:]@W + b) @ V   (u never materialized)
//   a = softmax_T(scores); out[b,f] = sum_t a[b,t]*x[b,t,f]
//
// R4: flash-style fusion — each GEMM block computes chunk-local softmax
// (m_c, l_c) over its 128 rows and the locally-weighted partial pooled sum
// by re-reading its own (L2-hot) x tile; a tiny combine kernel rescales the
// 32 chunks per batch. x's second HBM pass is eliminated/overlapped.
// K-loop reverted to R2 form (R3's manual prefetch regressed: 290->306us).

#define XT 4096
#define XF 512
#define XU 512

typedef __attribute__((ext_vector_type(8))) short short8;
typedef __attribute__((ext_vector_type(16))) float f32x16;

__device__ inline void cvt_hilo(float x, unsigned short &h, unsigned short &l) {
  unsigned u = __builtin_bit_cast(unsigned, x);
  h = (unsigned short)(u >> 16);                       // truncated bf16 hi
  float hf = __builtin_bit_cast(float, u & 0xFFFF0000u);
  float lo = x - hf;                                   // exact residual
  l = (unsigned short)(__builtin_bit_cast(unsigned, lo) >> 16);
}

__device__ inline float tanh_fast(float z) {
  float e = __expf(2.0f * z);
  return 1.0f - 2.0f * __builtin_amdgcn_rcpf(e + 1.0f);
}

// ---- W pre-conversion: fp32 [512 k][512 n] -> bf16 hi/lo, fragment-ready:
// whi/wlo: [slice s(32)][chunk16B: t(16)*64 + g(2)*32 + l(32)][j(8)]
// element = W[k = s*16 + g*8 + j][n = t*32 + l]
__global__ void wconv_kernel(const float *__restrict__ W,
                             unsigned short *__restrict__ whi,
                             unsigned short *__restrict__ wlo) {
  int t2 = blockIdx.x * 256 + threadIdx.x;  // 32768 threads
  int l = t2 & 31;
  int g = (t2 >> 5) & 1;
  int t = (t2 >> 6) & 15;
  int s = t2 >> 10;
  short8 hv, lv;
#pragma unroll
  for (int j = 0; j < 8; ++j) {
    unsigned short h, lo;
    cvt_hilo(W[(size_t)(s * 16 + g * 8 + j) * XU + t * 32 + l], h, lo);
    hv[j] = (short)h;
    lv[j] = (short)lo;
  }
  size_t off = (size_t)s * 8192 + t * 512 + g * 256 + l * 8;
  *(short8 *)(whi + off) = hv;
  *(short8 *)(wlo + off) = lv;
}

#define MFMA(a, b, c) __builtin_amdgcn_mfma_f32_32x32x16_bf16(a, b, c, 0, 0, 0)

// ---- fused GEMM + tanh + (.@V) + chunk-local softmax + weighted pooling
// block: 512 thr = 8 waves; tile 128 rows x 512 cols (one chunk of one batch).
// Emits partial[block][512] and pstats[block] = (m_c, l_c).
__global__ __launch_bounds__(512, 2)
void gemm_scores_kernel(const float *__restrict__ x,
                        const unsigned short *__restrict__ whi,
                        const unsigned short *__restrict__ wlo,
                        const float *__restrict__ bias,
                        const float *__restrict__ V,
                        float *__restrict__ partial,
                        float *__restrict__ pstats) {
  __shared__ float scb[512];   // per-wave-quarter partial scores
  __shared__ float warr[128];  // chunk-local softmax weights e^{s-m}
  __shared__ float red[1536];  // pooling cross-rowgroup reduction

  const int tid = threadIdx.x;
  const int lane = tid & 63;
  const int wave = tid >> 6;
  const int wr = wave >> 2;   // row half (64 rows)
  const int wc = wave & 3;    // col quarter (128 cols)
  const int l31 = lane & 31;
  const int half = lane >> 5;
  const size_t rowbase = (size_t)blockIdx.x * 128;

  f32x16 acc[2][4];
#pragma unroll
  for (int a = 0; a < 2; ++a)
#pragma unroll
    for (int c = 0; c < 4; ++c)
#pragma unroll
      for (int r = 0; r < 16; ++r) acc[a][c][r] = 0.f;

  // A: row = rowbase + wr*64 + rf*32 + l31 ; k = s*16 + half*8 + j
  const float *xr0 = x + (rowbase + wr * 64 + l31) * XF + half * 8;
  const float *xr1 = xr0 + 32 * XF;
  const unsigned short *whp = whi + (size_t)(wc * 4) * 512 + lane * 8;
  const unsigned short *wlp = wlo + (size_t)(wc * 4) * 512 + lane * 8;

#pragma unroll 1
  for (int s = 0; s < 32; ++s) {
    short8 bh[4], bl[4];
    const unsigned short *p = whp + (size_t)s * 8192;
    const unsigned short *q = wlp + (size_t)s * 8192;
#pragma unroll
    for (int cf = 0; cf < 4; ++cf) {
      bh[cf] = *(const short8 *)(p + cf * 512);
      bl[cf] = *(const short8 *)(q + cf * 512);
    }
    float4 a00 = *(const float4 *)(xr0 + s * 16);
    float4 a01 = *(const float4 *)(xr0 + s * 16 + 4);
    float4 a10 = *(const float4 *)(xr1 + s * 16);
    float4 a11 = *(const float4 *)(xr1 + s * 16 + 4);

    short8 ah0, al0, ah1, al1;
    {
      float v0[8] = {a00.x, a00.y, a00.z, a00.w, a01.x, a01.y, a01.z, a01.w};
      float v1[8] = {a10.x, a10.y, a10.z, a10.w, a11.x, a11.y, a11.z, a11.w};
#pragma unroll
      for (int j = 0; j < 8; ++j) {
        unsigned short h, lo;
        cvt_hilo(v0[j], h, lo);
        ah0[j] = (short)h; al0[j] = (short)lo;
        cvt_hilo(v1[j], h, lo);
        ah1[j] = (short)h; al1[j] = (short)lo;
      }
    }

#pragma unroll
    for (int cf = 0; cf < 4; ++cf) {
      acc[0][cf] = MFMA(ah0, bh[cf], acc[0][cf]);
      acc[1][cf] = MFMA(ah1, bh[cf], acc[1][cf]);
      acc[0][cf] = MFMA(al0, bh[cf], acc[0][cf]);
      acc[1][cf] = MFMA(al1, bh[cf], acc[1][cf]);
      acc[0][cf] = MFMA(ah0, bl[cf], acc[0][cf]);
      acc[1][cf] = MFMA(ah1, bl[cf], acc[1][cf]);
    }
  }

  // ---- score epilogue: sc[row] = sum_n tanh(acc + b[n]) * V[n]
  // C/D 32x32: col n = l31 (+32*cf+128*wc); row = (r&3)+8*(r>>2)+4*half (+32*rf+64*wr)
  float sc[2][16];
#pragma unroll
  for (int rf = 0; rf < 2; ++rf)
#pragma unroll
    for (int r = 0; r < 16; ++r) sc[rf][r] = 0.f;

#pragma unroll
  for (int cf = 0; cf < 4; ++cf) {
    int n = wc * 128 + cf * 32 + l31;
    float vv = V[n];
    float bb = bias[n];
#pragma unroll
    for (int rf = 0; rf < 2; ++rf)
#pragma unroll
      for (int r = 0; r < 16; ++r)
        sc[rf][r] += tanh_fast(acc[rf][cf][r] + bb) * vv;
  }
#pragma unroll
  for (int m = 1; m <= 16; m <<= 1) {
#pragma unroll
    for (int rf = 0; rf < 2; ++rf)
#pragma unroll
      for (int r = 0; r < 16; ++r)
        sc[rf][r] += __shfl_xor(sc[rf][r], m, 64);
  }
  if (l31 == 0) {
#pragma unroll
    for (int rf = 0; rf < 2; ++rf)
#pragma unroll
      for (int r = 0; r < 16; ++r) {
        int row = wr * 64 + rf * 32 + (r & 3) + 8 * (r >> 2) + 4 * half;
        scb[wc * 128 + row] = sc[rf][r];
      }
  }
  __syncthreads();

  // ---- chunk-local softmax: s_t -> m_c, w_t = e^{s_t - m_c}
  __shared__ float sarr[128];
  if (tid < 128)
    sarr[tid] = scb[tid] + scb[128 + tid] + scb[256 + tid] + scb[384 + tid];
  __syncthreads();
  float mloc = -1e30f;
#pragma unroll 8
  for (int i = 0; i < 128; ++i) mloc = fmaxf(mloc, sarr[i]);
  if (tid < 128) warr[tid] = __expf(sarr[tid] - mloc);
  __syncthreads();

  // ---- weighted pooling over own (L2-hot) tile: 4 row-groups x 128 col4s
  const int rg = tid >> 7;   // 0..3 -> rows rg*32..+32
  const int c4 = tid & 127;  // float4 column
  const float *xp = x + rowbase * XF;
  float4 pa = {0.f, 0.f, 0.f, 0.f};
#pragma unroll 8
  for (int i = 0; i < 32; ++i) {
    int r = rg * 32 + i;
    float4 v = *(const float4 *)(xp + (size_t)r * XF + c4 * 4);
    float wv = warr[r];
    pa.x += wv * v.x;
    pa.y += wv * v.y;
    pa.z += wv * v.z;
    pa.w += wv * v.w;
  }
  if (rg > 0) {
    float *rp = red + (rg - 1) * 512 + c4 * 4;
    rp[0] = pa.x; rp[1] = pa.y; rp[2] = pa.z; rp[3] = pa.w;
  }
  __syncthreads();
  if (rg == 0) {
    const float *r0 = red + c4 * 4;
    float4 o;
    o.x = pa.x + r0[0] + r0[512] + r0[1024];
    o.y = pa.y + r0[1] + r0[513] + r0[1025];
    o.z = pa.z + r0[2] + r0[514] + r0[1026];
    o.w = pa.w + r0[3] + r0[515] + r0[1027];
    *(float4 *)(partial + (size_t)blockIdx.x * 512 + c4 * 4) = o;
  }
  if (tid == 0) {
    float l = 0.f;
#pragma unroll 8
    for (int i = 0; i < 128; ++i) l += warr[i];
    pstats[blockIdx.x * 2] = mloc;
    pstats[blockIdx.x * 2 + 1] = l;
  }
}

// ---- combine: out[b,f] = sum_c e^{m_c-M} partial[c][f] / (sum_c e^{m_c-M} l_c)
__global__ __launch_bounds__(512)
void combine_kernel(const float *__restrict__ partial,
                    const float *__restrict__ pstats,
                    float *__restrict__ out) {
  int b = blockIdx.x;
  int f = threadIdx.x;
  __shared__ float ml[32], ll[32];
  if (f < 32) {
    ml[f] = pstats[(b * 32 + f) * 2];
    ll[f] = pstats[(b * 32 + f) * 2 + 1];
  }
  __syncthreads();
  float M = -1e30f;
#pragma unroll
  for (int c = 0; c < 32; ++c) M = fmaxf(M, ml[c]);
  float L = 0.f;
#pragma unroll
  for (int c = 0; c < 32; ++c) L += __expf(ml[c] - M) * ll[c];
  float acc = 0.f;
#pragma unroll
  for (int c = 0; c < 32; ++c)
    acc += __expf(ml[c] - M) * partial[(size_t)(b * 32 + c) * 512 + f];
  out[b * XF + f] = acc / L;
}

extern "C" void kernel_launch(void *const *d_in, const int *in_sizes, int n_in,
                              void *d_out, int out_size, void *d_ws,
                              size_t ws_size, hipStream_t stream) {
  const float *x = (const float *)d_in[0];
  const float *W = (const float *)d_in[1];
  const float *bias = (const float *)d_in[2];
  const float *V = (const float *)d_in[3];
  float *out = (float *)d_out;

  // workspace: whi 512KB | wlo 512KB | partial 2MB | pstats 8KB
  unsigned short *whi = (unsigned short *)d_ws;
  unsigned short *wlo = whi + 262144;
  float *partial = (float *)((char *)d_ws + 1048576);
  float *pstats = (float *)((char *)d_ws + 1048576 + 2097152);

  wconv_kernel<<<128, 256, 0, stream>>>(W, whi, wlo);
  gemm_scores_kernel<<<1024, 512, 0, stream>>>(x, whi, wlo, bias, V, partial,
                                               pstats);
  combine_kernel<<<32, 512, 0, stream>>>(partial, pstats, out);
}